// Round 6
// baseline (417.345 us; speedup 1.0000x reference)
//
#include <hip/hip_runtime.h>
#include <hip/hip_bf16.h>

// ---------------------------------------------------------------------------
// BipartiteGConv, CSR-gather formulation (no fp atomics):
//   rhs = input @ Wi + bi                [N_IN,64]  f32
//   lhs = other @ Wo                     [N_OT,64]  bf16 (gather table)
//   CSR build: deg/hist -> exclusive scan -> scatter pay={lj,w} by dest row
//   fused: sacc[i] = sum_{e in row i} leaky(rhs[i]+lhs[lj_e]+w_e*We)  (regs)
//          res[i]  = sacc@Wcomb + deg[i]*bcomb + input[i]@WoutB + bout
//
// R5 lessons: scatter was random-write-line bound (2M lines for 8MB payload
// -> 102MB writeback); final re-read S needlessly. Fixes: 8B fused payload
// (1M lines), reduce+final fusion (S never hits memory).
// R4 lesson: row-GEMMs must be 8-row blocked (readlane bcast, 8x fewer LDS).
// R3 lesson: fp atomic scatter is atomic-op-throughput bound -> CSR.
// ---------------------------------------------------------------------------

static __device__ __forceinline__ float bf2f(unsigned u) {
    return __uint_as_float(u << 16);
}
static __device__ __forceinline__ unsigned f2bf(float f) {  // RNE
    unsigned u = __float_as_uint(f);
    return (u + 0x7fffu + ((u >> 16) & 1u)) >> 16;
}
static __device__ __forceinline__ float bcast(float v, int k) {  // wave broadcast
    return __int_as_float(__builtin_amdgcn_readlane(__float_as_int(v), k));
}

// Y[row] = X[row] @ W (+ b). R=8 rows per wave iteration; W staged in LDS.
template <bool BF16OUT>
__global__ void rowgemm64(const float* __restrict__ X, const float* __restrict__ W,
                          const float* __restrict__ b, void* __restrict__ Y, int N) {
    __shared__ float Ws[4096];
    for (int i = threadIdx.x; i < 4096; i += blockDim.x) Ws[i] = W[i];
    __syncthreads();
    const int lane = threadIdx.x & 63;
    const int wid  = threadIdx.x >> 6;
    const int wpb  = blockDim.x >> 6;
    const float bv = b ? b[lane] : 0.0f;
    const long long wglob = blockIdx.x * wpb + wid;
    const long long wtot  = (long long)gridDim.x * wpb;
    float* Yf = (float*)Y;
    unsigned short* Yb = (unsigned short*)Y;
    for (long long base = wglob * 8; base < N; base += wtot * 8) {
        if (base + 8 <= N) {
            float xv[8], acc[8];
#pragma unroll
            for (int r = 0; r < 8; ++r) {
                xv[r]  = X[(base + r) * 64 + lane];
                acc[r] = bv;
            }
#pragma unroll
            for (int k = 0; k < 64; ++k) {
                float wv = Ws[k * 64 + lane];
#pragma unroll
                for (int r = 0; r < 8; ++r) acc[r] = fmaf(bcast(xv[r], k), wv, acc[r]);
            }
#pragma unroll
            for (int r = 0; r < 8; ++r) {
                if (BF16OUT) Yb[(base + r) * 64 + lane] = (unsigned short)f2bf(acc[r]);
                else         Yf[(base + r) * 64 + lane] = acc[r];
            }
        } else {
            for (long long row = base; row < N; ++row) {
                float xv = X[row * 64 + lane], acc = bv;
#pragma unroll
                for (int k = 0; k < 64; ++k)
                    acc = fmaf(bcast(xv, k), Ws[k * 64 + lane], acc);
                if (BF16OUT) Yb[row * 64 + lane] = (unsigned short)f2bf(acc);
                else         Yf[row * 64 + lane] = acc;
            }
        }
    }
}

// Wcomb = Wf @ WoutA (64x64), bcomb = bf @ WoutA (64). WoutA = Wout rows 0..63.
__global__ void combine_w(const float* __restrict__ Wf, const float* __restrict__ bf,
                          const float* __restrict__ WoutA, float* __restrict__ Wcomb,
                          float* __restrict__ bcomb) {
    int id = blockIdx.x * blockDim.x + threadIdx.x;
    if (id < 4096) {
        int k = id >> 6, d = id & 63;
        float acc = 0.f;
#pragma unroll 8
        for (int j = 0; j < 64; ++j) acc = fmaf(Wf[k * 64 + j], WoutA[j * 64 + d], acc);
        Wcomb[id] = acc;
    } else if (id < 4160) {
        int d = id - 4096;
        float acc = 0.f;
#pragma unroll 8
        for (int j = 0; j < 64; ++j) acc = fmaf(bf[j], WoutA[j * 64 + d], acc);
        bcomb[d] = acc;
    }
}

// --- CSR build ---
__global__ void hist_kernel(const int* __restrict__ rj, int* __restrict__ deg, int E) {
    int i = blockIdx.x * blockDim.x + threadIdx.x, st = gridDim.x * blockDim.x;
    for (; i < E; i += st) atomicAdd(&deg[rj[i]], 1);
}

// Block-local exclusive scan (1024/block), Hillis-Steele in LDS.
__global__ void scan1_kernel(const int* __restrict__ deg, int* __restrict__ rowoff,
                             int* __restrict__ blksum, int N) {
    __shared__ int s[1024];
    const int tid = threadIdx.x;
    const int i = blockIdx.x * 1024 + tid;
    int v = (i < N) ? deg[i] : 0;
    s[tid] = v;
    __syncthreads();
    for (int off = 1; off < 1024; off <<= 1) {
        int t = (tid >= off) ? s[tid - off] : 0;
        __syncthreads();
        s[tid] += t;
        __syncthreads();
    }
    if (i < N) rowoff[i] = s[tid] - v;  // exclusive
    if (tid == 1023) blksum[blockIdx.x] = s[1023];
}

// Exclusive scan of block sums (nb <= 1024), in place.
__global__ void scan2_kernel(int* __restrict__ blksum, int nb) {
    __shared__ int s[1024];
    const int tid = threadIdx.x;
    int v = (tid < nb) ? blksum[tid] : 0;
    s[tid] = v;
    __syncthreads();
    for (int off = 1; off < 1024; off <<= 1) {
        int t = (tid >= off) ? s[tid - off] : 0;
        __syncthreads();
        s[tid] += t;
        __syncthreads();
    }
    if (tid < nb) blksum[tid] = s[tid] - v;
}

__global__ void scan3_kernel(int* __restrict__ rowoff, const int* __restrict__ blksum,
                             int* __restrict__ cursor, int N, int E) {
    int i = blockIdx.x * blockDim.x + threadIdx.x, st = gridDim.x * blockDim.x;
    for (; i < N; i += st) {
        int v = rowoff[i] + blksum[i >> 10];
        rowoff[i] = v;
        cursor[i] = v;
    }
    if (blockIdx.x == 0 && threadIdx.x == 0) rowoff[N] = E;
}

// Scatter fused edge payload {lj, w} into CSR order: one 8B store per edge.
__global__ void scatter_kernel(const int* __restrict__ rj, const int* __restrict__ lj,
                               const float* __restrict__ wts, int* __restrict__ cursor,
                               int2* __restrict__ pay, int E) {
    int i = blockIdx.x * blockDim.x + threadIdx.x, st = gridDim.x * blockDim.x;
    for (; i < E; i += st) {
        int r = rj[i];
        int pos = atomicAdd(&cursor[r], 1);
        pay[pos] = make_int2(lj[i], __float_as_int(wts[i]));
    }
}

// Fused segment-reduce + output GEMM. 8 rows per wave iteration.
// sacc (segment sum) never leaves registers; feeds GEMM via readlane bcast.
__global__ void reduce_final_kernel(const float* __restrict__ rhs,
                                    const unsigned short* __restrict__ lhs,
                                    const int2* __restrict__ pay,
                                    const float* __restrict__ We,
                                    const int* __restrict__ rowoff,
                                    const float* __restrict__ input,
                                    const float* __restrict__ Wcomb,
                                    const float* __restrict__ bcomb,
                                    const float* __restrict__ WoutB,
                                    const float* __restrict__ bout,
                                    float* __restrict__ out, int N) {
    __shared__ float WcS[4096];
    __shared__ float WbS[4096];
    for (int i = threadIdx.x; i < 4096; i += blockDim.x) {
        WcS[i] = Wcomb[i];
        WbS[i] = WoutB[i];
    }
    __syncthreads();
    const int lane = threadIdx.x & 63;
    const int wid  = threadIdx.x >> 6;
    const int wpb  = blockDim.x >> 6;
    const float wev = We[lane];
    const float bc  = bcomb[lane];
    const float bo  = bout[lane];
    const long long wglob = blockIdx.x * wpb + wid;
    const long long wtot  = (long long)gridDim.x * wpb;
    for (long long base = wglob * 8; base < N; base += wtot * 8) {
        if (base + 8 <= N) {
            float sacc[8], iv[8], acc[8];
#pragma unroll
            for (int r = 0; r < 8; ++r) {
                const long long row = base + r;
                const int beg = rowoff[row], end = rowoff[row + 1];
                const float rv = rhs[row * 64 + lane];
                iv[r] = input[row * 64 + lane];
                acc[r] = fmaf((float)(end - beg), bc, bo);
                float s = 0.f;
                int idx = beg;
                for (; idx + 4 <= end; idx += 4) {
                    int2 p0 = pay[idx], p1 = pay[idx + 1], p2 = pay[idx + 2], p3 = pay[idx + 3];
                    float a0 = bf2f(lhs[(size_t)p0.x * 64 + lane]);
                    float a1 = bf2f(lhs[(size_t)p1.x * 64 + lane]);
                    float a2 = bf2f(lhs[(size_t)p2.x * 64 + lane]);
                    float a3 = bf2f(lhs[(size_t)p3.x * 64 + lane]);
                    float m0 = rv + a0 + __int_as_float(p0.y) * wev;
                    float m1 = rv + a1 + __int_as_float(p1.y) * wev;
                    float m2 = rv + a2 + __int_as_float(p2.y) * wev;
                    float m3 = rv + a3 + __int_as_float(p3.y) * wev;
                    s += (m0 >= 0.f) ? m0 : 0.01f * m0;
                    s += (m1 >= 0.f) ? m1 : 0.01f * m1;
                    s += (m2 >= 0.f) ? m2 : 0.01f * m2;
                    s += (m3 >= 0.f) ? m3 : 0.01f * m3;
                }
                for (; idx < end; ++idx) {
                    int2 p = pay[idx];
                    float a = bf2f(lhs[(size_t)p.x * 64 + lane]);
                    float m = rv + a + __int_as_float(p.y) * wev;
                    s += (m >= 0.f) ? m : 0.01f * m;
                }
                sacc[r] = s;
            }
#pragma unroll
            for (int k = 0; k < 64; ++k) {
                float wc = WcS[k * 64 + lane];
                float wb = WbS[k * 64 + lane];
#pragma unroll
                for (int r = 0; r < 8; ++r) {
                    acc[r] = fmaf(bcast(sacc[r], k), wc, acc[r]);
                    acc[r] = fmaf(bcast(iv[r], k),   wb, acc[r]);
                }
            }
#pragma unroll
            for (int r = 0; r < 8; ++r) out[(base + r) * 64 + lane] = acc[r];
        } else {
            for (long long row = base; row < N; ++row) {
                const int beg = rowoff[row], end = rowoff[row + 1];
                const float rv = rhs[row * 64 + lane];
                const float ivs = input[row * 64 + lane];
                float s = 0.f;
                for (int idx = beg; idx < end; ++idx) {
                    int2 p = pay[idx];
                    float a = bf2f(lhs[(size_t)p.x * 64 + lane]);
                    float m = rv + a + __int_as_float(p.y) * wev;
                    s += (m >= 0.f) ? m : 0.01f * m;
                }
                float acc = fmaf((float)(end - beg), bc, bo);
#pragma unroll
                for (int k = 0; k < 64; ++k) {
                    acc = fmaf(bcast(s, k),   WcS[k * 64 + lane], acc);
                    acc = fmaf(bcast(ivs, k), WbS[k * 64 + lane], acc);
                }
                out[row * 64 + lane] = acc;
            }
        }
    }
}

extern "C" void kernel_launch(void* const* d_in, const int* in_sizes, int n_in,
                              void* d_out, int out_size, void* d_ws, size_t ws_size,
                              hipStream_t stream) {
    const float* input = (const float*)d_in[0];
    const float* other = (const float*)d_in[1];
    const int*   rj    = (const int*)d_in[2];
    const int*   lj    = (const int*)d_in[3];
    const float* wts   = (const float*)d_in[4];
    const float* Wi    = (const float*)d_in[5];
    const float* bi    = (const float*)d_in[6];
    const float* Wo    = (const float*)d_in[7];
    const float* We    = (const float*)d_in[8];
    const float* Wf    = (const float*)d_in[9];
    const float* bf    = (const float*)d_in[10];
    const float* Wout  = (const float*)d_in[11];
    const float* bout  = (const float*)d_in[12];
    float* out = (float*)d_out;

    const int N_IN = in_sizes[0] / 64;
    const int N_OT = in_sizes[1] / 64;
    const int E    = in_sizes[2];
    const int nb1  = (N_IN + 1023) / 1024;

    char* ws = (char*)d_ws;
    float* rhs   = (float*)ws; ws += (size_t)N_IN * 64 * sizeof(float);
    int2*  pay   = (int2*)ws;  ws += (size_t)E * sizeof(int2);
    float* Wcomb = (float*)ws; ws += 4096 * sizeof(float);
    float* bcomb = (float*)ws; ws += 64 * sizeof(float);
    int* deg     = (int*)ws;   ws += (size_t)N_IN * sizeof(int);
    int* rowoff  = (int*)ws;   ws += ((size_t)N_IN + 2) * sizeof(int);
    int* cursor  = (int*)ws;   ws += (size_t)N_IN * sizeof(int);
    int* blksum  = (int*)ws;   ws += 1024 * sizeof(int);
    unsigned short* lhs = (unsigned short*)ws; ws += (size_t)N_OT * 64 * sizeof(unsigned short);

    hipMemsetAsync(deg, 0, (size_t)N_IN * sizeof(int), stream);

    rowgemm64<false><<<2048, 256, 0, stream>>>(input, Wi, bi, rhs, N_IN);
    rowgemm64<true ><<<1024, 256, 0, stream>>>(other, Wo, nullptr, lhs, N_OT);
    combine_w<<<17, 256, 0, stream>>>(Wf, bf, Wout, Wcomb, bcomb);

    hist_kernel<<<1024, 256, 0, stream>>>(rj, deg, E);
    scan1_kernel<<<nb1, 1024, 0, stream>>>(deg, rowoff, blksum, N_IN);
    scan2_kernel<<<1, 1024, 0, stream>>>(blksum, nb1);
    scan3_kernel<<<256, 256, 0, stream>>>(rowoff, blksum, cursor, N_IN, E);
    scatter_kernel<<<1024, 256, 0, stream>>>(rj, lj, wts, cursor, pay, E);

    reduce_final_kernel<<<2048, 256, 0, stream>>>(rhs, lhs, pay, We, rowoff, input,
                                                  Wcomb, bcomb, Wout + 64 * 64, bout,
                                                  out, N_IN);
}

// Round 7
// 399.072 us; speedup vs baseline: 1.0458x; 1.0458x over previous
//
#include <hip/hip_runtime.h>
#include <hip/hip_bf16.h>

// ---------------------------------------------------------------------------
// BipartiteGConv, CSR-gather formulation (no fp atomics):
//   rhs = input @ Wi + bi                [N_IN,64]  bf16 (table)
//   lhs = other @ Wo                     [N_OT,64]  bf16 (gather table)
//   CSR build: deg/hist -> exclusive scan -> scatter pay={lj,w} by dest row
//   fused: sacc[i] = sum_{e in row i} leaky(rhs[i]+lhs[lj_e]+w_e*We)  (regs)
//          res[i]  = sacc@Wcomb + deg[i]*bcomb + input[i]@WoutB + bout
//
// R6 lesson: fused kernel concurrency-starved (occ 37% via 32KB LDS; 4-deep
// gather MLP; HBM 16%/VALU 46% both idle). Fixes: bf16 ushort2 weight LDS
// (16KB, 1 ds_read/k), 8-deep gather pipeline, bf16 rhs table.
// R5: scatter random-line writes -> 8B fused payload; S round-trip -> fusion.
// R4: row-GEMMs 8-row blocked w/ readlane bcast (8x fewer LDS reads).
// R3: fp atomic scatter hits 244 G/s TCC atomic ceiling -> CSR instead.
// ---------------------------------------------------------------------------

static __device__ __forceinline__ float bf2f(unsigned u) {
    return __uint_as_float(u << 16);
}
static __device__ __forceinline__ unsigned f2bf(float f) {  // RNE
    unsigned u = __float_as_uint(f);
    return (u + 0x7fffu + ((u >> 16) & 1u)) >> 16;
}
static __device__ __forceinline__ float bcast(float v, int k) {  // wave broadcast
    return __int_as_float(__builtin_amdgcn_readlane(__float_as_int(v), k));
}

// Y[row] = X[row] @ W (+ b), bf16 output. R=8 rows per wave iteration.
__global__ void rowgemm64(const float* __restrict__ X, const float* __restrict__ W,
                          const float* __restrict__ b, unsigned short* __restrict__ Y,
                          int N) {
    __shared__ float Ws[4096];
    for (int i = threadIdx.x; i < 4096; i += blockDim.x) Ws[i] = W[i];
    __syncthreads();
    const int lane = threadIdx.x & 63;
    const int wid  = threadIdx.x >> 6;
    const int wpb  = blockDim.x >> 6;
    const float bv = b ? b[lane] : 0.0f;
    const long long wglob = blockIdx.x * wpb + wid;
    const long long wtot  = (long long)gridDim.x * wpb;
    for (long long base = wglob * 8; base < N; base += wtot * 8) {
        if (base + 8 <= N) {
            float xv[8], acc[8];
#pragma unroll
            for (int r = 0; r < 8; ++r) {
                xv[r]  = X[(base + r) * 64 + lane];
                acc[r] = bv;
            }
#pragma unroll
            for (int k = 0; k < 64; ++k) {
                float wv = Ws[k * 64 + lane];
#pragma unroll
                for (int r = 0; r < 8; ++r) acc[r] = fmaf(bcast(xv[r], k), wv, acc[r]);
            }
#pragma unroll
            for (int r = 0; r < 8; ++r)
                Y[(base + r) * 64 + lane] = (unsigned short)f2bf(acc[r]);
        } else {
            for (long long row = base; row < N; ++row) {
                float xv = X[row * 64 + lane], acc = bv;
#pragma unroll
                for (int k = 0; k < 64; ++k)
                    acc = fmaf(bcast(xv, k), Ws[k * 64 + lane], acc);
                Y[row * 64 + lane] = (unsigned short)f2bf(acc);
            }
        }
    }
}

// Wcomb = Wf @ WoutA (64x64), bcomb = bf @ WoutA (64). WoutA = Wout rows 0..63.
__global__ void combine_w(const float* __restrict__ Wf, const float* __restrict__ bf,
                          const float* __restrict__ WoutA, float* __restrict__ Wcomb,
                          float* __restrict__ bcomb) {
    int id = blockIdx.x * blockDim.x + threadIdx.x;
    if (id < 4096) {
        int k = id >> 6, d = id & 63;
        float acc = 0.f;
#pragma unroll 8
        for (int j = 0; j < 64; ++j) acc = fmaf(Wf[k * 64 + j], WoutA[j * 64 + d], acc);
        Wcomb[id] = acc;
    } else if (id < 4160) {
        int d = id - 4096;
        float acc = 0.f;
#pragma unroll 8
        for (int j = 0; j < 64; ++j) acc = fmaf(bf[j], WoutA[j * 64 + d], acc);
        bcomb[d] = acc;
    }
}

// --- CSR build ---
__global__ void hist_kernel(const int* __restrict__ rj, int* __restrict__ deg, int E) {
    int i = blockIdx.x * blockDim.x + threadIdx.x, st = gridDim.x * blockDim.x;
    for (; i < E; i += st) atomicAdd(&deg[rj[i]], 1);
}

__global__ void scan1_kernel(const int* __restrict__ deg, int* __restrict__ rowoff,
                             int* __restrict__ blksum, int N) {
    __shared__ int s[1024];
    const int tid = threadIdx.x;
    const int i = blockIdx.x * 1024 + tid;
    int v = (i < N) ? deg[i] : 0;
    s[tid] = v;
    __syncthreads();
    for (int off = 1; off < 1024; off <<= 1) {
        int t = (tid >= off) ? s[tid - off] : 0;
        __syncthreads();
        s[tid] += t;
        __syncthreads();
    }
    if (i < N) rowoff[i] = s[tid] - v;  // exclusive
    if (tid == 1023) blksum[blockIdx.x] = s[1023];
}

__global__ void scan2_kernel(int* __restrict__ blksum, int nb) {
    __shared__ int s[1024];
    const int tid = threadIdx.x;
    int v = (tid < nb) ? blksum[tid] : 0;
    s[tid] = v;
    __syncthreads();
    for (int off = 1; off < 1024; off <<= 1) {
        int t = (tid >= off) ? s[tid - off] : 0;
        __syncthreads();
        s[tid] += t;
        __syncthreads();
    }
    if (tid < nb) blksum[tid] = s[tid] - v;
}

__global__ void scan3_kernel(int* __restrict__ rowoff, const int* __restrict__ blksum,
                             int* __restrict__ cursor, int N, int E) {
    int i = blockIdx.x * blockDim.x + threadIdx.x, st = gridDim.x * blockDim.x;
    for (; i < N; i += st) {
        int v = rowoff[i] + blksum[i >> 10];
        rowoff[i] = v;
        cursor[i] = v;
    }
    if (blockIdx.x == 0 && threadIdx.x == 0) rowoff[N] = E;
}

// Scatter fused edge payload {lj, w} into CSR order: one 8B store per edge.
__global__ void scatter_kernel(const int* __restrict__ rj, const int* __restrict__ lj,
                               const float* __restrict__ wts, int* __restrict__ cursor,
                               int2* __restrict__ pay, int E) {
    int i = blockIdx.x * blockDim.x + threadIdx.x, st = gridDim.x * blockDim.x;
    for (; i < E; i += st) {
        int r = rj[i];
        int pos = atomicAdd(&cursor[r], 1);
        pay[pos] = make_int2(lj[i], __float_as_int(wts[i]));
    }
}

// Fused segment-reduce + output GEMM. 8 rows/wave-iter; 8-deep gather pipe;
// bf16 ushort2-interleaved weights in 16KB LDS (occupancy lever, R6 lesson).
__global__ void reduce_final_kernel(const unsigned short* __restrict__ rhs,
                                    const unsigned short* __restrict__ lhs,
                                    const int2* __restrict__ pay,
                                    const float* __restrict__ We,
                                    const int* __restrict__ rowoff,
                                    const float* __restrict__ input,
                                    const float* __restrict__ Wcomb,
                                    const float* __restrict__ bcomb,
                                    const float* __restrict__ WoutB,
                                    const float* __restrict__ bout,
                                    float* __restrict__ out, int N) {
    __shared__ ushort2 WS[4096];  // 16 KB: {wc, wb} bf16 pairs, [k][lane]
    for (int i = threadIdx.x; i < 4096; i += blockDim.x)
        WS[i] = make_ushort2((unsigned short)f2bf(Wcomb[i]),
                             (unsigned short)f2bf(WoutB[i]));
    __syncthreads();
    const int lane = threadIdx.x & 63;
    const int wid  = threadIdx.x >> 6;
    const int wpb  = blockDim.x >> 6;
    const float wev = We[lane];
    const float bc  = bcomb[lane];
    const float bo  = bout[lane];
    const long long wglob = blockIdx.x * wpb + wid;
    const long long wtot  = (long long)gridDim.x * wpb;
    for (long long base = wglob * 8; base < N; base += wtot * 8) {
        if (base + 8 <= N) {
            float sacc[8], iv[8], acc[8];
#pragma unroll
            for (int r = 0; r < 8; ++r) {
                const long long row = base + r;
                const int beg = rowoff[row], end = rowoff[row + 1];
                const float rv = bf2f(rhs[row * 64 + lane]);
                iv[r] = input[row * 64 + lane];
                acc[r] = fmaf((float)(end - beg), bc, bo);
                float s = 0.f;
                int idx = beg;
                for (; idx + 8 <= end; idx += 8) {
                    int2 p[8];
#pragma unroll
                    for (int j = 0; j < 8; ++j) p[j] = pay[idx + j];
                    float a[8];
#pragma unroll
                    for (int j = 0; j < 8; ++j)
                        a[j] = bf2f(lhs[(size_t)p[j].x * 64 + lane]);
#pragma unroll
                    for (int j = 0; j < 8; ++j) {
                        float m = rv + a[j] + __int_as_float(p[j].y) * wev;
                        s += (m >= 0.f) ? m : 0.01f * m;
                    }
                }
                if (idx + 4 <= end) {
                    int2 p[4];
#pragma unroll
                    for (int j = 0; j < 4; ++j) p[j] = pay[idx + j];
#pragma unroll
                    for (int j = 0; j < 4; ++j) {
                        float m = rv + bf2f(lhs[(size_t)p[j].x * 64 + lane])
                                  + __int_as_float(p[j].y) * wev;
                        s += (m >= 0.f) ? m : 0.01f * m;
                    }
                    idx += 4;
                }
                for (; idx < end; ++idx) {
                    int2 p = pay[idx];
                    float m = rv + bf2f(lhs[(size_t)p.x * 64 + lane])
                              + __int_as_float(p.y) * wev;
                    s += (m >= 0.f) ? m : 0.01f * m;
                }
                sacc[r] = s;
            }
#pragma unroll
            for (int k = 0; k < 64; ++k) {
                ushort2 w = WS[k * 64 + lane];
                float wc = bf2f(w.x), wb = bf2f(w.y);
#pragma unroll
                for (int r = 0; r < 8; ++r) {
                    acc[r] = fmaf(bcast(sacc[r], k), wc,
                             fmaf(bcast(iv[r], k),   wb, acc[r]));
                }
            }
#pragma unroll
            for (int r = 0; r < 8; ++r) out[(base + r) * 64 + lane] = acc[r];
        } else {
            for (long long row = base; row < N; ++row) {
                const int beg = rowoff[row], end = rowoff[row + 1];
                const float rv = bf2f(rhs[row * 64 + lane]);
                const float ivs = input[row * 64 + lane];
                float s = 0.f;
                for (int idx = beg; idx < end; ++idx) {
                    int2 p = pay[idx];
                    float m = rv + bf2f(lhs[(size_t)p.x * 64 + lane])
                              + __int_as_float(p.y) * wev;
                    s += (m >= 0.f) ? m : 0.01f * m;
                }
                float acc = fmaf((float)(end - beg), bc, bo);
#pragma unroll
                for (int k = 0; k < 64; ++k) {
                    ushort2 w = WS[k * 64 + lane];
                    acc = fmaf(bcast(s, k),   bf2f(w.x),
                          fmaf(bcast(ivs, k), bf2f(w.y), acc));
                }
                out[row * 64 + lane] = acc;
            }
        }
    }
}

extern "C" void kernel_launch(void* const* d_in, const int* in_sizes, int n_in,
                              void* d_out, int out_size, void* d_ws, size_t ws_size,
                              hipStream_t stream) {
    const float* input = (const float*)d_in[0];
    const float* other = (const float*)d_in[1];
    const int*   rj    = (const int*)d_in[2];
    const int*   lj    = (const int*)d_in[3];
    const float* wts   = (const float*)d_in[4];
    const float* Wi    = (const float*)d_in[5];
    const float* bi    = (const float*)d_in[6];
    const float* Wo    = (const float*)d_in[7];
    const float* We    = (const float*)d_in[8];
    const float* Wf    = (const float*)d_in[9];
    const float* bf    = (const float*)d_in[10];
    const float* Wout  = (const float*)d_in[11];
    const float* bout  = (const float*)d_in[12];
    float* out = (float*)d_out;

    const int N_IN = in_sizes[0] / 64;
    const int N_OT = in_sizes[1] / 64;
    const int E    = in_sizes[2];
    const int nb1  = (N_IN + 1023) / 1024;

    char* ws = (char*)d_ws;
    int2*  pay   = (int2*)ws;  ws += (size_t)E * sizeof(int2);
    float* Wcomb = (float*)ws; ws += 4096 * sizeof(float);
    float* bcomb = (float*)ws; ws += 64 * sizeof(float);
    int* deg     = (int*)ws;   ws += (size_t)N_IN * sizeof(int);
    int* rowoff  = (int*)ws;   ws += ((size_t)N_IN + 2) * sizeof(int);
    int* cursor  = (int*)ws;   ws += (size_t)N_IN * sizeof(int);
    int* blksum  = (int*)ws;   ws += 1024 * sizeof(int);
    unsigned short* rhs = (unsigned short*)ws; ws += (size_t)N_IN * 64 * sizeof(unsigned short);
    unsigned short* lhs = (unsigned short*)ws; ws += (size_t)N_OT * 64 * sizeof(unsigned short);

    hipMemsetAsync(deg, 0, (size_t)N_IN * sizeof(int), stream);

    rowgemm64<<<2048, 256, 0, stream>>>(input, Wi, bi, rhs, N_IN);
    rowgemm64<<<1024, 256, 0, stream>>>(other, Wo, nullptr, lhs, N_OT);
    combine_w<<<17, 256, 0, stream>>>(Wf, bf, Wout, Wcomb, bcomb);

    hist_kernel<<<1024, 256, 0, stream>>>(rj, deg, E);
    scan1_kernel<<<nb1, 1024, 0, stream>>>(deg, rowoff, blksum, N_IN);
    scan2_kernel<<<1, 1024, 0, stream>>>(blksum, nb1);
    scan3_kernel<<<256, 256, 0, stream>>>(rowoff, blksum, cursor, N_IN, E);
    scatter_kernel<<<1024, 256, 0, stream>>>(rj, lj, wts, cursor, pay, E);

    reduce_final_kernel<<<2048, 256, 0, stream>>>(rhs, lhs, pay, We, rowoff, input,
                                                  Wcomb, bcomb, Wout + 64 * 64, bout,
                                                  out, N_IN);
}

// Round 8
// 300.006 us; speedup vs baseline: 1.3911x; 1.3302x over previous
//
#include <hip/hip_runtime.h>
#include <hip/hip_bf16.h>

// ---------------------------------------------------------------------------
// BipartiteGConv, CSR + MFMA formulation:
//   prep:  WiT/WoT bf16 transposed; WcatT[64,128] = [Wf@WoutA ; WoutB]^T bf16
//   rhs   = input @ Wi + bi   [N_IN,64] bf16   (MFMA, also emits input_bf16)
//   lhs   = other @ Wo        [N_OT,64] bf16   (MFMA)
//   CSR:   hist -> scan -> sweep-bucketed scatter pay={lj,w}
//   S[i]  = sum_e leaky(rhs[i]+lhs[lj_e]+w_e*We)   (1 wave/row, bf16 out)
//   out   = [S|input]@Wcat + deg*bcomb + bout      (MFMA, 16 rows/wave)
//
// R7: fused kernel's broadcast-FMA GEMM was ~2/3 of its 57% VALUBusy -> MFMA.
// R6: concurrency starvation -> de-fuse, 1 wave/row reduce, full occupancy.
// R5: scatter random 8B stores = 12x write-line amplification -> sweep buckets.
// R3: fp atomic scatter hits TCC atomic-op ceiling -> CSR, no fp atomics.
// ---------------------------------------------------------------------------

typedef short short8 __attribute__((ext_vector_type(8)));
typedef float f32x4  __attribute__((ext_vector_type(4)));

static __device__ __forceinline__ float bf2f(unsigned u) {
    return __uint_as_float(u << 16);
}
static __device__ __forceinline__ unsigned f2bf(float f) {  // RNE
    unsigned u = __float_as_uint(f);
    return (u + 0x7fffu + ((u >> 16) & 1u)) >> 16;
}

// Build transposed bf16 weight tables + combined output weights.
// WcatT[n][k] (64x128): k<64 -> (Wf@WoutA)^T, k>=64 -> Wout rows 64..127 ^T.
__global__ void prep_weights(const float* __restrict__ Wi, const float* __restrict__ Wo,
                             const float* __restrict__ Wf, const float* __restrict__ bf,
                             const float* __restrict__ Wout,
                             unsigned short* __restrict__ WiT,
                             unsigned short* __restrict__ WoT,
                             unsigned short* __restrict__ WcatT,
                             float* __restrict__ bcomb) {
    int id = blockIdx.x * blockDim.x + threadIdx.x;
    if (id < 8192) {                       // WcatT
        int n = id >> 7, k = id & 127;
        float v;
        if (k < 64) {
            v = 0.f;
#pragma unroll 8
            for (int j = 0; j < 64; ++j) v = fmaf(Wf[k * 64 + j], Wout[j * 64 + n], v);
        } else {
            v = Wout[k * 64 + n];
        }
        WcatT[id] = (unsigned short)f2bf(v);
    } else if (id < 8256) {                // bcomb
        int n = id - 8192;
        float v = 0.f;
#pragma unroll 8
        for (int j = 0; j < 64; ++j) v = fmaf(bf[j], Wout[j * 64 + n], v);
        bcomb[n] = v;
    } else if (id < 12352) {               // WiT[n][k] = Wi[k][n]
        int t = id - 8256, n = t >> 6, k = t & 63;
        WiT[t] = (unsigned short)f2bf(Wi[k * 64 + n]);
    } else if (id < 16448) {               // WoT
        int t = id - 12352, n = t >> 6, k = t & 63;
        WoT[t] = (unsigned short)f2bf(Wo[k * 64 + n]);
    }
}

// Y[N,64] = bf16(X f32 @ W + b) via MFMA; 16 rows/wave; optionally emits
// bf16 copy of X. WT is W^T bf16 [64,64]. A-frag: lane holds row (l&15),
// k = s*32 + (l>>4)*8 + j  -> contiguous 16B loads, no LDS.
__global__ void mfma_rowgemm(const float* __restrict__ X,
                             const unsigned short* __restrict__ WT,
                             const float* __restrict__ b,
                             unsigned short* __restrict__ Y,
                             unsigned short* __restrict__ Xb, int N) {
    const int lane = threadIdx.x & 63;
    const int wave = (blockIdx.x * blockDim.x + threadIdx.x) >> 6;
    const long long base = (long long)wave * 16;
    if (base >= N) return;
    const int r15 = lane & 15, hi = lane >> 4;
    long long arow = base + r15;
    if (arow >= N) arow = N - 1;

    short8 afr[2];
#pragma unroll
    for (int s = 0; s < 2; ++s) {
        const int kb = s * 32 + hi * 8;
        const float* px = X + arow * 64 + kb;
        float4 x0 = *(const float4*)px;
        float4 x1 = *(const float4*)(px + 4);
        short8 a;
        a[0] = (short)f2bf(x0.x); a[1] = (short)f2bf(x0.y);
        a[2] = (short)f2bf(x0.z); a[3] = (short)f2bf(x0.w);
        a[4] = (short)f2bf(x1.x); a[5] = (short)f2bf(x1.y);
        a[6] = (short)f2bf(x1.z); a[7] = (short)f2bf(x1.w);
        afr[s] = a;
        if (Xb) *(short8*)(Xb + arow * 64 + kb) = a;  // clamped rows rewrite same data
    }
    const f32x4 z = {0.f, 0.f, 0.f, 0.f};
    f32x4 acc[4] = {z, z, z, z};
#pragma unroll
    for (int t = 0; t < 4; ++t)
#pragma unroll
        for (int s = 0; s < 2; ++s) {
            short8 bb = *(const short8*)(WT + (t * 16 + r15) * 64 + s * 32 + hi * 8);
            acc[t] = __builtin_amdgcn_mfma_f32_16x16x32_bf16(afr[s], bb, acc[t], 0, 0, 0);
        }
#pragma unroll
    for (int t = 0; t < 4; ++t) {
        const int col = t * 16 + r15;
        const float bv = b ? b[col] : 0.f;
#pragma unroll
        for (int j = 0; j < 4; ++j) {
            long long row = base + hi * 4 + j;
            if (row < N) Y[row * 64 + col] = (unsigned short)f2bf(acc[t][j] + bv);
        }
    }
}

// --- CSR build ---
__global__ void hist_kernel(const int* __restrict__ rj, int* __restrict__ deg, int E) {
    int i = blockIdx.x * blockDim.x + threadIdx.x, st = gridDim.x * blockDim.x;
    for (; i < E; i += st) atomicAdd(&deg[rj[i]], 1);
}

__global__ void scan1_kernel(const int* __restrict__ deg, int* __restrict__ rowoff,
                             int* __restrict__ blksum, int N) {
    __shared__ int s[1024];
    const int tid = threadIdx.x;
    const int i = blockIdx.x * 1024 + tid;
    int v = (i < N) ? deg[i] : 0;
    s[tid] = v;
    __syncthreads();
    for (int off = 1; off < 1024; off <<= 1) {
        int t = (tid >= off) ? s[tid - off] : 0;
        __syncthreads();
        s[tid] += t;
        __syncthreads();
    }
    if (i < N) rowoff[i] = s[tid] - v;
    if (tid == 1023) blksum[blockIdx.x] = s[1023];
}

__global__ void scan2_kernel(int* __restrict__ blksum, int nb) {
    __shared__ int s[1024];
    const int tid = threadIdx.x;
    int v = (tid < nb) ? blksum[tid] : 0;
    s[tid] = v;
    __syncthreads();
    for (int off = 1; off < 1024; off <<= 1) {
        int t = (tid >= off) ? s[tid - off] : 0;
        __syncthreads();
        s[tid] += t;
        __syncthreads();
    }
    if (tid < nb) blksum[tid] = s[tid] - v;
}

__global__ void scan3_kernel(int* __restrict__ rowoff, const int* __restrict__ blksum,
                             int* __restrict__ cursor, int N, int E) {
    int i = blockIdx.x * blockDim.x + threadIdx.x, st = gridDim.x * blockDim.x;
    for (; i < N; i += st) {
        int v = rowoff[i] + blksum[i >> 10];
        rowoff[i] = v;
        cursor[i] = v;
    }
    if (blockIdx.x == 0 && threadIdx.x == 0) rowoff[N] = E;
}

// Sweep-bucketed scatter: pass s handles rows with rj>>14 == s, confining the
// random pay writes to a ~1.3MB cache-resident window (R5: 12x write ampl.).
__global__ void scatter_kernel(const int* __restrict__ rj, const int* __restrict__ lj,
                               const float* __restrict__ wts, int* __restrict__ cursor,
                               int2* __restrict__ pay, int E) {
    const int tid0 = blockIdx.x * blockDim.x + threadIdx.x;
    const int st = gridDim.x * blockDim.x;
    for (int s = 0; s <= 6; ++s) {
        for (int i = tid0; i < E; i += st) {
            int r = rj[i];
            if ((r >> 14) == s) {
                int pos = atomicAdd(&cursor[r], 1);
                pay[pos] = make_int2(lj[i], __float_as_int(wts[i]));
            }
        }
    }
}

// Segment reduce, 1 wave/row, 8-deep gather pipeline. S out bf16.
__global__ void reduce_kernel(const unsigned short* __restrict__ rhs,
                              const unsigned short* __restrict__ lhs,
                              const int2* __restrict__ pay,
                              const float* __restrict__ We,
                              const int* __restrict__ rowoff,
                              unsigned short* __restrict__ S, int N) {
    const int lane = threadIdx.x & 63;
    const int wid  = threadIdx.x >> 6;
    const int wpb  = blockDim.x >> 6;
    const float wev = We[lane];
    const int w0 = blockIdx.x * wpb + wid;
    const int wtot = gridDim.x * wpb;
    for (int row = w0; row < N; row += wtot) {
        const int beg = rowoff[row], end = rowoff[row + 1];
        const float rv = bf2f(rhs[(size_t)row * 64 + lane]);
        float s = 0.f;
        int idx = beg;
        for (; idx + 8 <= end; idx += 8) {
            int2 p[8];
#pragma unroll
            for (int j = 0; j < 8; ++j) p[j] = pay[idx + j];
            float a[8];
#pragma unroll
            for (int j = 0; j < 8; ++j) a[j] = bf2f(lhs[(size_t)p[j].x * 64 + lane]);
#pragma unroll
            for (int j = 0; j < 8; ++j) {
                float m = rv + a[j] + __int_as_float(p[j].y) * wev;
                s += (m >= 0.f) ? m : 0.01f * m;
            }
        }
        if (idx + 4 <= end) {
            int2 p[4];
#pragma unroll
            for (int j = 0; j < 4; ++j) p[j] = pay[idx + j];
#pragma unroll
            for (int j = 0; j < 4; ++j) {
                float m = rv + bf2f(lhs[(size_t)p[j].x * 64 + lane])
                          + __int_as_float(p[j].y) * wev;
                s += (m >= 0.f) ? m : 0.01f * m;
            }
            idx += 4;
        }
        for (; idx < end; ++idx) {
            int2 p = pay[idx];
            float m = rv + bf2f(lhs[(size_t)p.x * 64 + lane])
                      + __int_as_float(p.y) * wev;
            s += (m >= 0.f) ? m : 0.01f * m;
        }
        S[(size_t)row * 64 + lane] = (unsigned short)f2bf(s);
    }
}

// out = [S|input_bf]@Wcat + deg*bcomb + bout, MFMA, 16 rows/wave.
__global__ void final_mfma(const unsigned short* __restrict__ S,
                           const unsigned short* __restrict__ Xb,
                           const unsigned short* __restrict__ WcatT,
                           const float* __restrict__ bcomb,
                           const float* __restrict__ bout,
                           const int* __restrict__ deg,
                           float* __restrict__ out, int N) {
    const int lane = threadIdx.x & 63;
    const int wave = (blockIdx.x * blockDim.x + threadIdx.x) >> 6;
    const long long base = (long long)wave * 16;
    if (base >= N) return;
    const int r15 = lane & 15, hi = lane >> 4;
    long long arow = base + r15;
    if (arow >= N) arow = N - 1;

    short8 afr[4];
#pragma unroll
    for (int s = 0; s < 2; ++s)
        afr[s] = *(const short8*)(S + arow * 64 + s * 32 + hi * 8);
#pragma unroll
    for (int s = 0; s < 2; ++s)
        afr[2 + s] = *(const short8*)(Xb + arow * 64 + s * 32 + hi * 8);

    const f32x4 z = {0.f, 0.f, 0.f, 0.f};
    f32x4 acc[4] = {z, z, z, z};
#pragma unroll
    for (int t = 0; t < 4; ++t)
#pragma unroll
        for (int s = 0; s < 4; ++s) {
            short8 bb = *(const short8*)(WcatT + (t * 16 + r15) * 128 + s * 32 + hi * 8);
            acc[t] = __builtin_amdgcn_mfma_f32_16x16x32_bf16(afr[s], bb, acc[t], 0, 0, 0);
        }

    float dj[4];
#pragma unroll
    for (int j = 0; j < 4; ++j) {
        long long rr = base + hi * 4 + j;
        dj[j] = (rr < N) ? (float)deg[rr] : 0.f;
    }
#pragma unroll
    for (int t = 0; t < 4; ++t) {
        const int col = t * 16 + r15;
        const float bc = bcomb[col];
        const float bo = bout[col];
#pragma unroll
        for (int j = 0; j < 4; ++j) {
            long long rr = base + hi * 4 + j;
            if (rr < N) out[rr * 64 + col] = fmaf(dj[j], bc, acc[t][j] + bo);
        }
    }
}

extern "C" void kernel_launch(void* const* d_in, const int* in_sizes, int n_in,
                              void* d_out, int out_size, void* d_ws, size_t ws_size,
                              hipStream_t stream) {
    const float* input = (const float*)d_in[0];
    const float* other = (const float*)d_in[1];
    const int*   rj    = (const int*)d_in[2];
    const int*   lj    = (const int*)d_in[3];
    const float* wts   = (const float*)d_in[4];
    const float* Wi    = (const float*)d_in[5];
    const float* bi    = (const float*)d_in[6];
    const float* Wo    = (const float*)d_in[7];
    const float* We    = (const float*)d_in[8];
    const float* Wf    = (const float*)d_in[9];
    const float* bf    = (const float*)d_in[10];
    const float* Wout  = (const float*)d_in[11];
    const float* bout  = (const float*)d_in[12];
    float* out = (float*)d_out;

    const int N_IN = in_sizes[0] / 64;
    const int N_OT = in_sizes[1] / 64;
    const int E    = in_sizes[2];
    const int nb1  = (N_IN + 1023) / 1024;

    char* ws = (char*)d_ws;
    int2* pay = (int2*)ws;                        ws += (size_t)E * sizeof(int2);
    unsigned short* WiT   = (unsigned short*)ws;  ws += 4096 * 2;
    unsigned short* WoT   = (unsigned short*)ws;  ws += 4096 * 2;
    unsigned short* WcatT = (unsigned short*)ws;  ws += 8192 * 2;
    float* bcomb = (float*)ws;                    ws += 64 * sizeof(float);
    int* deg     = (int*)ws;                      ws += (size_t)N_IN * sizeof(int);
    int* rowoff  = (int*)ws;                      ws += ((size_t)N_IN + 2) * sizeof(int);
    int* cursor  = (int*)ws;                      ws += (size_t)N_IN * sizeof(int);
    int* blksum  = (int*)ws;                      ws += 1024 * sizeof(int);
    unsigned short* rhs = (unsigned short*)ws;    ws += (size_t)N_IN * 64 * 2;
    unsigned short* lhs = (unsigned short*)ws;    ws += (size_t)N_OT * 64 * 2;
    unsigned short* S   = (unsigned short*)ws;    ws += (size_t)N_IN * 64 * 2;
    unsigned short* Xb  = (unsigned short*)ws;    ws += (size_t)N_IN * 64 * 2;

    hipMemsetAsync(deg, 0, (size_t)N_IN * sizeof(int), stream);

    prep_weights<<<65, 256, 0, stream>>>(Wi, Wo, Wf, bf, Wout, WiT, WoT, WcatT, bcomb);

    const int gbA = (N_IN + 63) / 64;  // 4 waves/block * 16 rows/wave
    const int gbB = (N_OT + 63) / 64;
    mfma_rowgemm<<<gbA, 256, 0, stream>>>(input, WiT, bi, rhs, Xb, N_IN);
    mfma_rowgemm<<<gbB, 256, 0, stream>>>(other, WoT, nullptr, lhs, nullptr, N_OT);

    hist_kernel<<<1024, 256, 0, stream>>>(rj, deg, E);
    scan1_kernel<<<nb1, 1024, 0, stream>>>(deg, rowoff, blksum, N_IN);
    scan2_kernel<<<1, 1024, 0, stream>>>(blksum, nb1);
    scan3_kernel<<<256, 256, 0, stream>>>(rowoff, blksum, cursor, N_IN, E);
    scatter_kernel<<<1024, 256, 0, stream>>>(rj, lj, wts, cursor, pay, E);

    reduce_kernel<<<2048, 256, 0, stream>>>(rhs, lhs, pay, We, rowoff, S, N_IN);
    final_mfma<<<gbA, 256, 0, stream>>>(S, Xb, WcatT, bcomb, bout, deg, out, N_IN);
}

// Round 9
// 293.804 us; speedup vs baseline: 1.4205x; 1.0211x over previous
//
#include <hip/hip_runtime.h>
#include <hip/hip_bf16.h>

// ---------------------------------------------------------------------------
// BipartiteGConv, CSR + MFMA formulation:
//   prep:  WiT/WoT bf16 transposed; WcatT[64,128] = [Wf@WoutA ; WoutB]^T bf16
//   rhs   = input @ Wi + bi   [N_IN,64] bf16   (MFMA, also emits input_bf16)
//   lhs   = other @ Wo        [N_OT,64] bf16   (MFMA)
//   CSR:   pack+hist -> scan -> XCD-bucketed scatter pay={u16 lj, bf16 w}
//   S[i]  = sum_e leaky(rhs[i]+lhs[lj_e]+w_e*We)   (1 wave/row, bf16 out)
//   out   = [S|input]@Wcat + deg*bcomb + bout      (MFMA, 16 rows/wave)
//
// R8: scatter WRITE 61.7MB for 8MB payload = per-XCD L2 line ping-pong (8
//     XCDs each dirty every line). Fix: bucket-by-XCD (group g=blockIdx&7
//     owns rows ((r>>13)&7)==g) + 4B packed payload.
// R7: broadcast-FMA GEMMs -> MFMA (16 rows/wave, no LDS).
// R6: fused kernel concurrency-starved -> de-fused, 1 wave/row reduce.
// R5: random scatter stores -> write-line amplification; pack payloads.
// R3: fp atomic scatter hits TCC atomic-op ceiling -> CSR, no fp atomics.
// ---------------------------------------------------------------------------

typedef short short8 __attribute__((ext_vector_type(8)));
typedef float f32x4  __attribute__((ext_vector_type(4)));

static __device__ __forceinline__ float bf2f(unsigned u) {
    return __uint_as_float(u << 16);
}
static __device__ __forceinline__ unsigned f2bf(float f) {  // RNE
    unsigned u = __float_as_uint(f);
    return (u + 0x7fffu + ((u >> 16) & 1u)) >> 16;
}

// Build transposed bf16 weight tables + combined output weights.
__global__ void prep_weights(const float* __restrict__ Wi, const float* __restrict__ Wo,
                             const float* __restrict__ Wf, const float* __restrict__ bf,
                             const float* __restrict__ Wout,
                             unsigned short* __restrict__ WiT,
                             unsigned short* __restrict__ WoT,
                             unsigned short* __restrict__ WcatT,
                             float* __restrict__ bcomb) {
    int id = blockIdx.x * blockDim.x + threadIdx.x;
    if (id < 8192) {                       // WcatT[n][k]
        int n = id >> 7, k = id & 127;
        float v;
        if (k < 64) {
            v = 0.f;
#pragma unroll 8
            for (int j = 0; j < 64; ++j) v = fmaf(Wf[k * 64 + j], Wout[j * 64 + n], v);
        } else {
            v = Wout[k * 64 + n];
        }
        WcatT[id] = (unsigned short)f2bf(v);
    } else if (id < 8256) {                // bcomb
        int n = id - 8192;
        float v = 0.f;
#pragma unroll 8
        for (int j = 0; j < 64; ++j) v = fmaf(bf[j], Wout[j * 64 + n], v);
        bcomb[n] = v;
    } else if (id < 12352) {               // WiT[n][k] = Wi[k][n]
        int t = id - 8256, n = t >> 6, k = t & 63;
        WiT[t] = (unsigned short)f2bf(Wi[k * 64 + n]);
    } else if (id < 16448) {               // WoT
        int t = id - 12352, n = t >> 6, k = t & 63;
        WoT[t] = (unsigned short)f2bf(Wo[k * 64 + n]);
    }
}

// Y[N,64] = bf16(X f32 @ W + b) via MFMA; 16 rows/wave; optional bf16 X copy.
__global__ void mfma_rowgemm(const float* __restrict__ X,
                             const unsigned short* __restrict__ WT,
                             const float* __restrict__ b,
                             unsigned short* __restrict__ Y,
                             unsigned short* __restrict__ Xb, int N) {
    const int lane = threadIdx.x & 63;
    const int wave = (blockIdx.x * blockDim.x + threadIdx.x) >> 6;
    const long long base = (long long)wave * 16;
    if (base >= N) return;
    const int r15 = lane & 15, hi = lane >> 4;
    long long arow = base + r15;
    if (arow >= N) arow = N - 1;

    short8 afr[2];
#pragma unroll
    for (int s = 0; s < 2; ++s) {
        const int kb = s * 32 + hi * 8;
        const float* px = X + arow * 64 + kb;
        float4 x0 = *(const float4*)px;
        float4 x1 = *(const float4*)(px + 4);
        short8 a;
        a[0] = (short)f2bf(x0.x); a[1] = (short)f2bf(x0.y);
        a[2] = (short)f2bf(x0.z); a[3] = (short)f2bf(x0.w);
        a[4] = (short)f2bf(x1.x); a[5] = (short)f2bf(x1.y);
        a[6] = (short)f2bf(x1.z); a[7] = (short)f2bf(x1.w);
        afr[s] = a;
        if (Xb) *(short8*)(Xb + arow * 64 + kb) = a;
    }
    const f32x4 z = {0.f, 0.f, 0.f, 0.f};
    f32x4 acc[4] = {z, z, z, z};
#pragma unroll
    for (int t = 0; t < 4; ++t)
#pragma unroll
        for (int s = 0; s < 2; ++s) {
            short8 bb = *(const short8*)(WT + (t * 16 + r15) * 64 + s * 32 + hi * 8);
            acc[t] = __builtin_amdgcn_mfma_f32_16x16x32_bf16(afr[s], bb, acc[t], 0, 0, 0);
        }
#pragma unroll
    for (int t = 0; t < 4; ++t) {
        const int col = t * 16 + r15;
        const float bv = b ? b[col] : 0.f;
#pragma unroll
        for (int j = 0; j < 4; ++j) {
            long long row = base + hi * 4 + j;
            if (row < N) Y[row * 64 + col] = (unsigned short)f2bf(acc[t][j] + bv);
        }
    }
}

// Fused: deg histogram + packed payload {u16 lj, bf16 w} (needs N_OT<=65536).
__global__ void pack_hist_kernel(const int* __restrict__ rj, const int* __restrict__ lj,
                                 const float* __restrict__ wts,
                                 unsigned* __restrict__ pk, int* __restrict__ deg,
                                 int E) {
    int i = blockIdx.x * blockDim.x + threadIdx.x, st = gridDim.x * blockDim.x;
    for (; i < E; i += st) {
        atomicAdd(&deg[rj[i]], 1);
        pk[i] = (unsigned)lj[i] | (f2bf(wts[i]) << 16);
    }
}

__global__ void scan1_kernel(const int* __restrict__ deg, int* __restrict__ rowoff,
                             int* __restrict__ blksum, int N) {
    __shared__ int s[1024];
    const int tid = threadIdx.x;
    const int i = blockIdx.x * 1024 + tid;
    int v = (i < N) ? deg[i] : 0;
    s[tid] = v;
    __syncthreads();
    for (int off = 1; off < 1024; off <<= 1) {
        int t = (tid >= off) ? s[tid - off] : 0;
        __syncthreads();
        s[tid] += t;
        __syncthreads();
    }
    if (i < N) rowoff[i] = s[tid] - v;
    if (tid == 1023) blksum[blockIdx.x] = s[1023];
}

__global__ void scan2_kernel(int* __restrict__ blksum, int nb) {
    __shared__ int s[1024];
    const int tid = threadIdx.x;
    int v = (tid < nb) ? blksum[tid] : 0;
    s[tid] = v;
    __syncthreads();
    for (int off = 1; off < 1024; off <<= 1) {
        int t = (tid >= off) ? s[tid - off] : 0;
        __syncthreads();
        s[tid] += t;
        __syncthreads();
    }
    if (tid < nb) blksum[tid] = s[tid] - v;
}

__global__ void scan3_kernel(int* __restrict__ rowoff, const int* __restrict__ blksum,
                             int* __restrict__ cursor, int N, int E) {
    int i = blockIdx.x * blockDim.x + threadIdx.x, st = gridDim.x * blockDim.x;
    for (; i < N; i += st) {
        int v = rowoff[i] + blksum[i >> 10];
        rowoff[i] = v;
        cursor[i] = v;
    }
    if (blockIdx.x == 0 && threadIdx.x == 0) rowoff[N] = E;
}

// XCD-bucketed scatter: group g = blockIdx&7 (-> XCD g, round-robin heuristic)
// exclusively owns rows with ((r>>13)&7)==g, so each pay cache line is written
// by ONE XCD's L2 (R8: cross-XCD line ping-pong was 8x write amplification).
// Row-disjoint groups -> no cursor races across groups. Perf-only heuristic.
__global__ void scatter_kernel(const int* __restrict__ rj, const unsigned* __restrict__ pk,
                               int* __restrict__ cursor, unsigned* __restrict__ pay,
                               int E) {
    const int g    = blockIdx.x & 7;
    const int gblk = blockIdx.x >> 3;
    const int st   = (gridDim.x >> 3) * blockDim.x;
    for (int i = gblk * blockDim.x + threadIdx.x; i < E; i += st) {
        int r = rj[i];
        if (((r >> 13) & 7) == g) {
            int pos = atomicAdd(&cursor[r], 1);
            pay[pos] = pk[i];
        }
    }
}

// Segment reduce, 1 wave/row, 8-deep gather pipeline. S out bf16.
__global__ void reduce_kernel(const unsigned short* __restrict__ rhs,
                              const unsigned short* __restrict__ lhs,
                              const unsigned* __restrict__ pay,
                              const float* __restrict__ We,
                              const int* __restrict__ rowoff,
                              unsigned short* __restrict__ S, int N) {
    const int lane = threadIdx.x & 63;
    const int wid  = threadIdx.x >> 6;
    const int wpb  = blockDim.x >> 6;
    const float wev = We[lane];
    const int w0 = blockIdx.x * wpb + wid;
    const int wtot = gridDim.x * wpb;
    for (int row = w0; row < N; row += wtot) {
        const int beg = rowoff[row], end = rowoff[row + 1];
        const float rv = bf2f(rhs[(size_t)row * 64 + lane]);
        float s = 0.f;
        int idx = beg;
        for (; idx + 8 <= end; idx += 8) {
            unsigned p[8];
#pragma unroll
            for (int j = 0; j < 8; ++j) p[j] = pay[idx + j];
            float a[8];
#pragma unroll
            for (int j = 0; j < 8; ++j)
                a[j] = bf2f(lhs[(size_t)(p[j] & 0xffffu) * 64 + lane]);
#pragma unroll
            for (int j = 0; j < 8; ++j) {
                float m = rv + a[j] + bf2f(p[j] >> 16) * wev;
                s += (m >= 0.f) ? m : 0.01f * m;
            }
        }
        if (idx + 4 <= end) {
            unsigned p[4];
#pragma unroll
            for (int j = 0; j < 4; ++j) p[j] = pay[idx + j];
#pragma unroll
            for (int j = 0; j < 4; ++j) {
                float m = rv + bf2f(lhs[(size_t)(p[j] & 0xffffu) * 64 + lane])
                          + bf2f(p[j] >> 16) * wev;
                s += (m >= 0.f) ? m : 0.01f * m;
            }
            idx += 4;
        }
        for (; idx < end; ++idx) {
            unsigned p = pay[idx];
            float m = rv + bf2f(lhs[(size_t)(p & 0xffffu) * 64 + lane])
                      + bf2f(p >> 16) * wev;
            s += (m >= 0.f) ? m : 0.01f * m;
        }
        S[(size_t)row * 64 + lane] = (unsigned short)f2bf(s);
    }
}

// out = [S|input_bf]@Wcat + deg*bcomb + bout, MFMA, 16 rows/wave.
__global__ void final_mfma(const unsigned short* __restrict__ S,
                           const unsigned short* __restrict__ Xb,
                           const unsigned short* __restrict__ WcatT,
                           const float* __restrict__ bcomb,
                           const float* __restrict__ bout,
                           const int* __restrict__ deg,
                           float* __restrict__ out, int N) {
    const int lane = threadIdx.x & 63;
    const int wave = (blockIdx.x * blockDim.x + threadIdx.x) >> 6;
    const long long base = (long long)wave * 16;
    if (base >= N) return;
    const int r15 = lane & 15, hi = lane >> 4;
    long long arow = base + r15;
    if (arow >= N) arow = N - 1;

    short8 afr[4];
#pragma unroll
    for (int s = 0; s < 2; ++s)
        afr[s] = *(const short8*)(S + arow * 64 + s * 32 + hi * 8);
#pragma unroll
    for (int s = 0; s < 2; ++s)
        afr[2 + s] = *(const short8*)(Xb + arow * 64 + s * 32 + hi * 8);

    const f32x4 z = {0.f, 0.f, 0.f, 0.f};
    f32x4 acc[4] = {z, z, z, z};
#pragma unroll
    for (int t = 0; t < 4; ++t)
#pragma unroll
        for (int s = 0; s < 4; ++s) {
            short8 bb = *(const short8*)(WcatT + (t * 16 + r15) * 128 + s * 32 + hi * 8);
            acc[t] = __builtin_amdgcn_mfma_f32_16x16x32_bf16(afr[s], bb, acc[t], 0, 0, 0);
        }

    float dj[4];
#pragma unroll
    for (int j = 0; j < 4; ++j) {
        long long rr = base + hi * 4 + j;
        dj[j] = (rr < N) ? (float)deg[rr] : 0.f;
    }
#pragma unroll
    for (int t = 0; t < 4; ++t) {
        const int col = t * 16 + r15;
        const float bc = bcomb[col];
        const float bo = bout[col];
#pragma unroll
        for (int j = 0; j < 4; ++j) {
            long long rr = base + hi * 4 + j;
            if (rr < N) out[rr * 64 + col] = fmaf(dj[j], bc, acc[t][j] + bo);
        }
    }
}

extern "C" void kernel_launch(void* const* d_in, const int* in_sizes, int n_in,
                              void* d_out, int out_size, void* d_ws, size_t ws_size,
                              hipStream_t stream) {
    const float* input = (const float*)d_in[0];
    const float* other = (const float*)d_in[1];
    const int*   rj    = (const int*)d_in[2];
    const int*   lj    = (const int*)d_in[3];
    const float* wts   = (const float*)d_in[4];
    const float* Wi    = (const float*)d_in[5];
    const float* bi    = (const float*)d_in[6];
    const float* Wo    = (const float*)d_in[7];
    const float* We    = (const float*)d_in[8];
    const float* Wf    = (const float*)d_in[9];
    const float* bf    = (const float*)d_in[10];
    const float* Wout  = (const float*)d_in[11];
    const float* bout  = (const float*)d_in[12];
    float* out = (float*)d_out;

    const int N_IN = in_sizes[0] / 64;
    const int N_OT = in_sizes[1] / 64;
    const int E    = in_sizes[2];
    const int nb1  = (N_IN + 1023) / 1024;

    char* ws = (char*)d_ws;
    unsigned* pay = (unsigned*)ws;                ws += (size_t)E * sizeof(unsigned);
    unsigned* pk  = (unsigned*)ws;                ws += (size_t)E * sizeof(unsigned);
    unsigned short* WiT   = (unsigned short*)ws;  ws += 4096 * 2;
    unsigned short* WoT   = (unsigned short*)ws;  ws += 4096 * 2;
    unsigned short* WcatT = (unsigned short*)ws;  ws += 8192 * 2;
    float* bcomb = (float*)ws;                    ws += 64 * sizeof(float);
    int* deg     = (int*)ws;                      ws += (size_t)N_IN * sizeof(int);
    int* rowoff  = (int*)ws;                      ws += ((size_t)N_IN + 2) * sizeof(int);
    int* cursor  = (int*)ws;                      ws += (size_t)N_IN * sizeof(int);
    int* blksum  = (int*)ws;                      ws += 1024 * sizeof(int);
    unsigned short* rhs = (unsigned short*)ws;    ws += (size_t)N_IN * 64 * 2;
    unsigned short* lhs = (unsigned short*)ws;    ws += (size_t)N_OT * 64 * 2;
    unsigned short* S   = (unsigned short*)ws;    ws += (size_t)N_IN * 64 * 2;
    unsigned short* Xb  = (unsigned short*)ws;    ws += (size_t)N_IN * 64 * 2;

    hipMemsetAsync(deg, 0, (size_t)N_IN * sizeof(int), stream);

    prep_weights<<<65, 256, 0, stream>>>(Wi, Wo, Wf, bf, Wout, WiT, WoT, WcatT, bcomb);

    const int gbA = (N_IN + 63) / 64;  // 4 waves/block * 16 rows/wave
    const int gbB = (N_OT + 63) / 64;
    mfma_rowgemm<<<gbA, 256, 0, stream>>>(input, WiT, bi, rhs, Xb, N_IN);
    mfma_rowgemm<<<gbB, 256, 0, stream>>>(other, WoT, nullptr, lhs, nullptr, N_OT);

    pack_hist_kernel<<<1024, 256, 0, stream>>>(rj, lj, wts, pk, deg, E);
    scan1_kernel<<<nb1, 1024, 0, stream>>>(deg, rowoff, blksum, N_IN);
    scan2_kernel<<<1, 1024, 0, stream>>>(blksum, nb1);
    scan3_kernel<<<256, 256, 0, stream>>>(rowoff, blksum, cursor, N_IN, E);
    scatter_kernel<<<1024, 256, 0, stream>>>(rj, pk, cursor, pay, E);

    reduce_kernel<<<2048, 256, 0, stream>>>(rhs, lhs, pay, We, rowoff, S, N_IN);
    final_mfma<<<gbA, 256, 0, stream>>>(S, Xb, WcatT, bcomb, bout, deg, out, N_IN);
}